// Round 14
// baseline (198.759 us; speedup 1.0000x reference)
//
#include <hip/hip_runtime.h>
#include <hip/hip_bf16.h>
#include <cstdint>
#include <cstddef>

#define S_LEN 2048
#define D_MODEL 1024
#define N_HEADS 16
#define DEPTH 64
#define BATCH 4

#define GLOBAL_AS __attribute__((address_space(1)))
#define LDS_AS __attribute__((address_space(3)))

typedef __attribute__((ext_vector_type(4))) float f32x4;
typedef __attribute__((ext_vector_type(8))) short bf16x8;
typedef __attribute__((ext_vector_type(4))) unsigned short us4;
typedef __attribute__((ext_vector_type(8))) unsigned short us8;

__device__ __forceinline__ unsigned short f2bf(float f) {
  unsigned int u = __builtin_bit_cast(unsigned int, f);
  u += 0x7FFFu + ((u >> 16) & 1u);   // round-to-nearest-even
  return (unsigned short)(u >> 16);
}

__device__ __forceinline__ unsigned short f2bf_hw(float f) {
  return __builtin_bit_cast(unsigned short, __float2bfloat16(f));
}

// ---------------------------------------------------------------------------
// Fused weight transpose + scale + fp32 -> bf16 cast for all 4 weights.
// ---------------------------------------------------------------------------
struct TCArgs {
  const float* W[4];
  unsigned short* Wt[4];
  float scale[4];
};

__global__ __launch_bounds__(256) void transpose_cast4(TCArgs a, int N) {
  __shared__ float tile[32][33];
  int z = blockIdx.z;
  const float* W = a.W[z];
  unsigned short* Wt = a.Wt[z];
  float scale = a.scale[z];
  int bx = blockIdx.x * 32;
  int by = blockIdx.y * 32;
  int tx = threadIdx.x, ty = threadIdx.y;  // 32 x 8
#pragma unroll
  for (int i = 0; i < 4; ++i)
    tile[ty + i * 8][tx] = W[(size_t)(by + ty + i * 8) * N + bx + tx];
  __syncthreads();
#pragma unroll
  for (int i = 0; i < 4; ++i)
    Wt[(size_t)(bx + ty + i * 8) * N + by + tx] = f2bf(tile[tx][ty + i * 8] * scale);
}

// ---------------------------------------------------------------------------
// Per-head V transpose: Vp [B,S,D] bf16 -> Vt [B*H][DEPTH][S] bf16
// ---------------------------------------------------------------------------
__global__ __launch_bounds__(256) void transpose_v(const unsigned short* __restrict__ Vp,
                                                   unsigned short* __restrict__ Vt) {
  __shared__ unsigned short tile[64][72];
  int tid = threadIdx.x;
  int sb = blockIdx.x;
  int bh = blockIdx.y;
  int b = bh >> 4, h = bh & 15;
  int s0 = sb * 64;
#pragma unroll
  for (int rep = 0; rep < 2; ++rep) {
    int idx = rep * 256 + tid;
    int r = idx >> 3, c8 = idx & 7;
    us8 v = *(const us8*)(Vp + (size_t)(b * S_LEN + s0 + r) * D_MODEL + h * DEPTH + c8 * 8);
#pragma unroll
    for (int e = 0; e < 8; ++e) tile[c8 * 8 + e][r] = v[e];
  }
  __syncthreads();
#pragma unroll
  for (int rep = 0; rep < 2; ++rep) {
    int idx = rep * 256 + tid;
    int d = idx >> 3, c8 = idx & 7;
    us8 v = *(const us8*)&tile[d][c8 * 8];
    *(us8*)(Vt + ((size_t)(bh * DEPTH + d)) * S_LEN + s0 + c8 * 8) = v;
  }
}

// ---------------------------------------------------------------------------
// GEMM (r9 form verbatim — best measured: QKV 97us): 128x128 tile, 4 waves,
// reg-staged 2-barrier K-loop + T14 register prefetch of tile k+1 for BOTH
// operands. bf16-A path (AO) via global_load_lds with XOR-swizzled source +
// matching read XOR. No min-waves bound (r6/r8: silent spill catastrophes).
// r12 lesson: BM=256@512thr squeezes VGPR to 80 -> compiler serializes the
// prefetch; stay at the 256-thr/4-wave operating point.
// ---------------------------------------------------------------------------
struct GemmSlice {
  const void* A;
  const unsigned short* Bt;
  const float* bias;
  void* C;
  float bscale;
};
struct GemmArgs {
  GemmSlice s[3];
};

template <bool A_IS_F32, bool OUT_F32>
__global__ __launch_bounds__(256) void gemm_bt(GemmArgs args, int M, int N, int K) {
  constexpr int ASTR = A_IS_F32 ? 72 : 64;
  __shared__ unsigned short a_lds[128 * ASTR];
  __shared__ unsigned short b_lds[128 * 72];

  int slice = blockIdx.y >> 3;
  int nj = blockIdx.y & 7;
  const GemmSlice& g = args.s[slice];
  const float* Af = (const float*)g.A;
  const unsigned short* Ah = (const unsigned short*)g.A;
  const unsigned short* Bt = g.Bt;

  int tid = threadIdx.x;
  int wave = tid >> 6, lane = tid & 63;
  int l15 = lane & 15, lg = lane >> 4;
  int wm = wave >> 1, wn = wave & 1;

  int row0 = blockIdx.x * 128;
  int col0 = nj * 128;

  f32x4 acc[4][4] = {};
  f32x4 av[8];  // in-flight A tile (fp32 path)
  us8 bv[4];    // in-flight B tile

  int ar = tid >> 4, ac4 = tid & 15;  // fp32-A staging coords
  int br = tid >> 3, bc8 = tid & 7;   // B staging coords

  auto loadA = [&](int k0) {
#pragma unroll
    for (int rep = 0; rep < 8; ++rep)
      av[rep] = *(const f32x4*)(Af + (size_t)(row0 + rep * 16 + ar) * K + k0 + ac4 * 4);
  };
  auto writeA = [&]() {
#pragma unroll
    for (int rep = 0; rep < 8; ++rep) {
      us4 h = {f2bf_hw(av[rep][0]), f2bf_hw(av[rep][1]),
               f2bf_hw(av[rep][2]), f2bf_hw(av[rep][3])};
      *(us4*)&a_lds[(rep * 16 + ar) * 72 + ac4 * 4] = h;
    }
  };
  auto loadB = [&](int k0) {
#pragma unroll
    for (int rep = 0; rep < 4; ++rep)
      bv[rep] = *(const us8*)(Bt + (size_t)(col0 + rep * 32 + br) * K + k0 + bc8 * 8);
  };
  auto writeB = [&]() {
#pragma unroll
    for (int rep = 0; rep < 4; ++rep)
      *(us8*)&b_lds[(rep * 32 + br) * 72 + bc8 * 8] = bv[rep];
  };
  auto issueA = [&](int k0) {  // bf16-A via glds, swizzled source
#pragma unroll
    for (int rep = 0; rep < 4; ++rep) {
      int chunk = (wave * 4 + rep) * 64 + lane;
      int row = chunk >> 3;
      int c8 = (chunk & 7) ^ (row & 7);
      __builtin_amdgcn_global_load_lds(
          (const GLOBAL_AS void*)(Ah + (size_t)(row0 + row) * K + k0 + c8 * 8),
          (LDS_AS void*)(&a_lds[chunk * 8]), 16, 0, 0);
    }
  };
  auto compute = [&]() {
#pragma unroll
    for (int kk = 0; kk < 2; ++kk) {
      bf16x8 af[4], bfr[4];
#pragma unroll
      for (int ii = 0; ii < 4; ++ii) {
        int row = wm * 64 + ii * 16 + l15;
        if constexpr (A_IS_F32)
          af[ii] = *(const bf16x8*)&a_lds[row * 72 + kk * 32 + lg * 8];
        else
          af[ii] = *(const bf16x8*)&a_lds[row * 64 + (((kk * 4 + lg) ^ (l15 & 7)) * 8)];
      }
#pragma unroll
      for (int jj = 0; jj < 4; ++jj) {
        int row = wn * 64 + jj * 16 + l15;
        bfr[jj] = *(const bf16x8*)&b_lds[row * 72 + kk * 32 + lg * 8];
      }
#pragma unroll
      for (int ii = 0; ii < 4; ++ii)
#pragma unroll
        for (int jj = 0; jj < 4; ++jj)
          acc[ii][jj] = __builtin_amdgcn_mfma_f32_16x16x32_bf16(af[ii], bfr[jj], acc[ii][jj], 0, 0, 0);
    }
  };

  int nk = K >> 6;
  loadB(0);
  if constexpr (A_IS_F32) loadA(0);

  for (int ki = 0; ki < nk; ++ki) {
    __syncthreads();  // readers of previous tile done
    writeB();
    if constexpr (A_IS_F32)
      writeA();
    else
      issueA(ki * 64);
    __syncthreads();  // tile visible (drains lgkm + vmcnt)
    if (ki + 1 < nk) {
      loadB((ki + 1) * 64);                    // T14: prefetch next tile's regs —
      if constexpr (A_IS_F32) loadA((ki + 1) * 64);  // latency hides under MFMAs
    }
    compute();
  }

  // ---- epilogue ----
#pragma unroll
  for (int ii = 0; ii < 4; ++ii) {
#pragma unroll
    for (int jj = 0; jj < 4; ++jj) {
      int col = col0 + wn * 64 + jj * 16 + l15;
      float bv2 = g.bias[col] * g.bscale;
#pragma unroll
      for (int r = 0; r < 4; ++r) {
        int row = row0 + wm * 64 + ii * 16 + lg * 4 + r;
        float v = acc[ii][jj][r] + bv2;
        if constexpr (OUT_F32)
          ((float*)g.C)[(size_t)row * N + col] = v;
        else
          ((unsigned short*)g.C)[(size_t)row * N + col] = f2bf(v);
      }
    }
  }
}

// ---------------------------------------------------------------------------
// Causal flash attention. Q pre-scaled by 0.125*log2(e); NO-MAX exp2
// softmax; l via ones-MFMA. 32 q-rows/wave (r10 body: K/V LDS reads
// amortize over 2x MFMAs, reads/MFMA 0.55->0.46) at FIXED occupancy:
// grid 1024 x 256 thr -> 4 blocks/CU x 4 waves = 16 waves/CU (r10's loss
// was 8 waves/CU at grid 512). Per-CU work made uniform: the 4 co-resident
// blocks (same bh,j; g=0..3) get t in {j, 7-j, 8+j, 15-j} -> sum const=68
// steps, and each bh covers t=0..15 exactly once (bijective).
// ---------------------------------------------------------------------------
__global__ __launch_bounds__(256) void attn_kernel(const unsigned short* __restrict__ Qp,
                                                   const unsigned short* __restrict__ Kp,
                                                   const unsigned short* __restrict__ Vt,
                                                   unsigned short* __restrict__ Op) {
  __shared__ unsigned short k_lds[64][76];
  __shared__ unsigned short vt_lds[64][76];   // [d][k]
  __shared__ unsigned short p_lds[4][32][76];

  int tid = threadIdx.x;
  int w = tid >> 6, lane = tid & 63;
  int l15 = lane & 15, lg = lane >> 4;

  int bid = blockIdx.x;            // 0..1023
  int g = bid >> 8;                // 0..3 (co-resident group)
  int rr8 = bid & 255;
  int bh = rr8 >> 2, j = rr8 & 3;
  int t = (g == 0) ? j : (g == 1) ? (7 - j) : (g == 2) ? (8 + j) : (15 - j);
  int b = bh >> 4, h = bh & 15;

  int q0 = t * 128;
  int nkv = 2 * t + 2;

  const unsigned short* Kbase = Kp + (size_t)b * S_LEN * D_MODEL + h * DEPTH;
  const unsigned short* Vbase = Vt + (size_t)bh * DEPTH * S_LEN;

  // staging: threads 0-127 stage K (64x64), 128-255 stage V^T (64x64)
  bool stageV = (tid >= 128);
  int st = tid & 127;
  int r = st >> 1, cb = (st & 1) * 32;
  const unsigned short* srow = stageV ? (Vbase + (size_t)r * S_LEN + cb)
                                      : (Kbase + (size_t)r * D_MODEL + cb);
  const size_t sstep = stageV ? 64 : (size_t)64 * D_MODEL;

  bf16x8 ones;
#pragma unroll
  for (int e = 0; e < 8; ++e) ones[e] = (short)0x3F80;

  int qa0 = q0 + w * 32;  // group a rows: qa0..qa0+15; group b: +16..+31

  const unsigned short* qp =
      Qp + ((size_t)(b * S_LEN + qa0 + l15)) * D_MODEL + h * DEPTH;
  bf16x8 qa_0 = *(const bf16x8*)(qp + lg * 8);
  bf16x8 qa_1 = *(const bf16x8*)(qp + 32 + lg * 8);
  bf16x8 qb_0 = *(const bf16x8*)(qp + 16 * D_MODEL + lg * 8);
  bf16x8 qb_1 = *(const bf16x8*)(qp + 16 * D_MODEL + 32 + lg * 8);

  f32x4 acc_la = (f32x4){0.f, 0.f, 0.f, 0.f};
  f32x4 acc_lb = (f32x4){0.f, 0.f, 0.f, 0.f};
  f32x4 acc_oa[4], acc_ob[4];
#pragma unroll
  for (int dd = 0; dd < 4; ++dd) {
    acc_oa[dd] = (f32x4){0.f, 0.f, 0.f, 0.f};
    acc_ob[dd] = (f32x4){0.f, 0.f, 0.f, 0.f};
  }

  // prologue: load tile 0 into regs (4 x us8 = 64B per thread)
  const unsigned short* sptr = srow;
  us8 s0 = *(const us8*)sptr;
  us8 s1 = *(const us8*)(sptr + 8);
  us8 s2 = *(const us8*)(sptr + 16);
  us8 s3 = *(const us8*)(sptr + 24);
  sptr += sstep;

  for (int kb = 0; kb < nkv; ++kb) {
    int k0 = kb * 64;
    __syncthreads();  // readers of tile kb-1 done
    if (stageV) {
      *(us8*)&vt_lds[r][cb] = s0;
      *(us8*)&vt_lds[r][cb + 8] = s1;
      *(us8*)&vt_lds[r][cb + 16] = s2;
      *(us8*)&vt_lds[r][cb + 24] = s3;
    } else {
      *(us8*)&k_lds[r][cb] = s0;
      *(us8*)&k_lds[r][cb + 8] = s1;
      *(us8*)&k_lds[r][cb + 16] = s2;
      *(us8*)&k_lds[r][cb + 24] = s3;
    }
    __syncthreads();  // tile kb visible
    bool more = (kb + 1) < nkv;
    if (more) {
      s0 = *(const us8*)sptr;        // T14: issue next tile's loads early;
      s1 = *(const us8*)(sptr + 8);  // latency hides under compute below
      s2 = *(const us8*)(sptr + 16);
      s3 = *(const us8*)(sptr + 24);
      sptr += sstep;
    }

    bool doA = k0 <= qa0 + 15;   // group a not fully masked
    bool doB = k0 <= qa0 + 31;   // group b not fully masked
    if (doB) {
      // ---- S = Q @ K^T (kf read once, used by both q-groups) ----
      f32x4 sa[4], sb[4];
#pragma unroll
      for (int nf = 0; nf < 4; ++nf) {
        sa[nf] = (f32x4){0.f, 0.f, 0.f, 0.f};
        sb[nf] = (f32x4){0.f, 0.f, 0.f, 0.f};
      }
      __builtin_amdgcn_s_setprio(1);
#pragma unroll
      for (int nf = 0; nf < 4; ++nf) {
        bf16x8 kf0 = *(const bf16x8*)&k_lds[nf * 16 + l15][lg * 8];
        bf16x8 kf1 = *(const bf16x8*)&k_lds[nf * 16 + l15][32 + lg * 8];
        sb[nf] = __builtin_amdgcn_mfma_f32_16x16x32_bf16(qb_0, kf0, sb[nf], 0, 0, 0);
        sb[nf] = __builtin_amdgcn_mfma_f32_16x16x32_bf16(qb_1, kf1, sb[nf], 0, 0, 0);
        if (doA) {
          sa[nf] = __builtin_amdgcn_mfma_f32_16x16x32_bf16(qa_0, kf0, sa[nf], 0, 0, 0);
          sa[nf] = __builtin_amdgcn_mfma_f32_16x16x32_bf16(qa_1, kf1, sa[nf], 0, 0, 0);
        }
      }
      __builtin_amdgcn_s_setprio(0);

      // ---- P = exp2(S) with causal mask; truncating bf16 cast ----
      bool diagB = (k0 + 63 > qa0 + 16);
      if (diagB) {
#pragma unroll
        for (int nf = 0; nf < 4; ++nf)
#pragma unroll
          for (int rr = 0; rr < 4; ++rr) {
            int qrow = qa0 + 16 + lg * 4 + rr;
            int kcol = k0 + nf * 16 + l15;
            float x = (kcol > qrow) ? -1e10f : sb[nf][rr];
            float p = __builtin_amdgcn_exp2f(x);
            p_lds[w][16 + lg * 4 + rr][nf * 16 + l15] =
                (unsigned short)(__builtin_bit_cast(unsigned int, p) >> 16);
          }
      } else {
#pragma unroll
        for (int nf = 0; nf < 4; ++nf)
#pragma unroll
          for (int rr = 0; rr < 4; ++rr) {
            float p = __builtin_amdgcn_exp2f(sb[nf][rr]);
            p_lds[w][16 + lg * 4 + rr][nf * 16 + l15] =
                (unsigned short)(__builtin_bit_cast(unsigned int, p) >> 16);
          }
      }
      if (doA) {
        bool diagA = (k0 + 63 > qa0);
        if (diagA) {
#pragma unroll
          for (int nf = 0; nf < 4; ++nf)
#pragma unroll
            for (int rr = 0; rr < 4; ++rr) {
              int qrow = qa0 + lg * 4 + rr;
              int kcol = k0 + nf * 16 + l15;
              float x = (kcol > qrow) ? -1e10f : sa[nf][rr];
              float p = __builtin_amdgcn_exp2f(x);
              p_lds[w][lg * 4 + rr][nf * 16 + l15] =
                  (unsigned short)(__builtin_bit_cast(unsigned int, p) >> 16);
            }
        } else {
#pragma unroll
          for (int nf = 0; nf < 4; ++nf)
#pragma unroll
            for (int rr = 0; rr < 4; ++rr) {
              float p = __builtin_amdgcn_exp2f(sa[nf][rr]);
              p_lds[w][lg * 4 + rr][nf * 16 + l15] =
                  (unsigned short)(__builtin_bit_cast(unsigned int, p) >> 16);
            }
        }
      }

      // ---- O += P @ V ; l += P @ 1 (vf read once, both groups) ----
      __builtin_amdgcn_s_setprio(1);
#pragma unroll
      for (int kk = 0; kk < 2; ++kk) {
        bf16x8 vf[4];
#pragma unroll
        for (int dd = 0; dd < 4; ++dd)
          vf[dd] = *(const bf16x8*)&vt_lds[dd * 16 + l15][kk * 32 + lg * 8];
        bf16x8 pfb = *(const bf16x8*)&p_lds[w][16 + l15][kk * 32 + lg * 8];
        acc_lb = __builtin_amdgcn_mfma_f32_16x16x32_bf16(pfb, ones, acc_lb, 0, 0, 0);
#pragma unroll
        for (int dd = 0; dd < 4; ++dd)
          acc_ob[dd] = __builtin_amdgcn_mfma_f32_16x16x32_bf16(pfb, vf[dd], acc_ob[dd], 0, 0, 0);
        if (doA) {
          bf16x8 pfa = *(const bf16x8*)&p_lds[w][l15][kk * 32 + lg * 8];
          acc_la = __builtin_amdgcn_mfma_f32_16x16x32_bf16(pfa, ones, acc_la, 0, 0, 0);
#pragma unroll
          for (int dd = 0; dd < 4; ++dd)
            acc_oa[dd] = __builtin_amdgcn_mfma_f32_16x16x32_bf16(pfa, vf[dd], acc_oa[dd], 0, 0, 0);
        }
      }
      __builtin_amdgcn_s_setprio(0);
    }
  }

  // ---- finalize both groups ----
#pragma unroll
  for (int rr = 0; rr < 4; ++rr) {
    float inva = 1.0f / acc_la[rr];
    float invb = 1.0f / acc_lb[rr];
    int qrowa = qa0 + lg * 4 + rr;
    unsigned short* opa = Op + ((size_t)(b * S_LEN + qrowa)) * D_MODEL + h * DEPTH;
    unsigned short* opb = opa + (size_t)16 * D_MODEL;
#pragma unroll
    for (int dd = 0; dd < 4; ++dd) {
      opa[dd * 16 + l15] = f2bf(acc_oa[dd][rr] * inva);
      opb[dd * 16 + l15] = f2bf(acc_ob[dd][rr] * invb);
    }
  }
}

// ---------------------------------------------------------------------------
extern "C" void kernel_launch(void* const* d_in, const int* in_sizes, int n_in,
                              void* d_out, int out_size, void* d_ws, size_t ws_size,
                              hipStream_t stream) {
  const float* q  = (const float*)d_in[0];
  const float* v  = (const float*)d_in[1];
  const float* k  = (const float*)d_in[2];
  const float* Wq = (const float*)d_in[3];
  const float* bq = (const float*)d_in[4];
  const float* Wk = (const float*)d_in[5];
  const float* bk = (const float*)d_in[6];
  const float* Wv = (const float*)d_in[7];
  const float* bv = (const float*)d_in[8];
  const float* Wo = (const float*)d_in[9];
  const float* bo = (const float*)d_in[10];

  char* ws = (char*)d_ws;
  const size_t WSZ = (size_t)D_MODEL * D_MODEL * 2;        // 2 MB per weight
  const size_t XSZ = (size_t)BATCH * S_LEN * D_MODEL * 2;  // 16 MB per activation
  unsigned short* Wqt = (unsigned short*)(ws);
  unsigned short* Wkt = (unsigned short*)(ws + WSZ);
  unsigned short* Wvt = (unsigned short*)(ws + 2 * WSZ);
  unsigned short* Wot = (unsigned short*)(ws + 3 * WSZ);
  unsigned short* Qp  = (unsigned short*)(ws + 4 * WSZ);
  unsigned short* Kp  = (unsigned short*)(ws + 4 * WSZ + XSZ);
  unsigned short* Vp  = (unsigned short*)(ws + 4 * WSZ + 2 * XSZ);
  unsigned short* Vtp = (unsigned short*)(ws + 4 * WSZ + 3 * XSZ);
  unsigned short* AO  = Vp;  // alias: Vp fully consumed by transpose_v before attn writes AO

  const float SCL = 0.125f * 1.4426950408889634f;
  const int M = BATCH * S_LEN;

  TCArgs tc{};
  tc.W[0] = Wq;  tc.Wt[0] = Wqt;  tc.scale[0] = SCL;
  tc.W[1] = Wk;  tc.Wt[1] = Wkt;  tc.scale[1] = 1.0f;
  tc.W[2] = Wv;  tc.Wt[2] = Wvt;  tc.scale[2] = 1.0f;
  tc.W[3] = Wo;  tc.Wt[3] = Wot;  tc.scale[3] = 1.0f;
  hipLaunchKernelGGL(transpose_cast4, dim3(D_MODEL / 32, D_MODEL / 32, 4), dim3(32, 8),
                     0, stream, tc, D_MODEL);

  GemmArgs qkv{};
  qkv.s[0] = GemmSlice{(const void*)q, Wqt, bq, (void*)Qp, SCL};
  qkv.s[1] = GemmSlice{(const void*)k, Wkt, bk, (void*)Kp, 1.0f};
  qkv.s[2] = GemmSlice{(const void*)v, Wvt, bv, (void*)Vp, 1.0f};
  hipLaunchKernelGGL((gemm_bt<true, false>), dim3(M / 128, 24), dim3(256), 0, stream,
                     qkv, M, D_MODEL, D_MODEL);

  hipLaunchKernelGGL(transpose_v, dim3(S_LEN / 64, BATCH * N_HEADS), dim3(256), 0, stream,
                     Vp, Vtp);

  hipLaunchKernelGGL(attn_kernel, dim3(1024), dim3(256), 0, stream, Qp, Kp, Vtp, AO);

  GemmArgs ao{};
  ao.s[0] = GemmSlice{(const void*)AO, Wot, bo, d_out, 1.0f};
  hipLaunchKernelGGL((gemm_bt<false, true>), dim3(M / 128, 8), dim3(256), 0, stream,
                     ao, M, D_MODEL, D_MODEL);
}

// Round 15
// 178.479 us; speedup vs baseline: 1.1136x; 1.1136x over previous
//
#include <hip/hip_runtime.h>
#include <hip/hip_bf16.h>
#include <cstdint>
#include <cstddef>

#define S_LEN 2048
#define D_MODEL 1024
#define N_HEADS 16
#define DEPTH 64
#define BATCH 4

#define GLOBAL_AS __attribute__((address_space(1)))
#define LDS_AS __attribute__((address_space(3)))

typedef __attribute__((ext_vector_type(4))) float f32x4;
typedef __attribute__((ext_vector_type(8))) short bf16x8;
typedef __attribute__((ext_vector_type(4))) unsigned short us4;
typedef __attribute__((ext_vector_type(8))) unsigned short us8;

__device__ __forceinline__ unsigned short f2bf(float f) {
  unsigned int u = __builtin_bit_cast(unsigned int, f);
  u += 0x7FFFu + ((u >> 16) & 1u);   // round-to-nearest-even
  return (unsigned short)(u >> 16);
}

// HW cast (compiler emits v_cvt_pk_bf16_f32 pairs)
__device__ __forceinline__ unsigned short f2bf_hw(float f) {
  return __builtin_bit_cast(unsigned short, __float2bfloat16(f));
}

// ---------------------------------------------------------------------------
// Fused weight transpose + scale + fp32 -> bf16 cast for all 4 weights:
// Wt[n][k] = W[k][n] * scale.  grid.z selects the weight.
// ---------------------------------------------------------------------------
struct TCArgs {
  const float* W[4];
  unsigned short* Wt[4];
  float scale[4];
};

__global__ __launch_bounds__(256) void transpose_cast4(TCArgs a, int N) {
  __shared__ float tile[32][33];
  int z = blockIdx.z;
  const float* W = a.W[z];
  unsigned short* Wt = a.Wt[z];
  float scale = a.scale[z];
  int bx = blockIdx.x * 32;  // n-range
  int by = blockIdx.y * 32;  // k-range
  int tx = threadIdx.x, ty = threadIdx.y;  // 32 x 8
#pragma unroll
  for (int i = 0; i < 4; ++i)
    tile[ty + i * 8][tx] = W[(size_t)(by + ty + i * 8) * N + bx + tx];
  __syncthreads();
#pragma unroll
  for (int i = 0; i < 4; ++i)
    Wt[(size_t)(bx + ty + i * 8) * N + by + tx] = f2bf(tile[tx][ty + i * 8] * scale);
}

// ---------------------------------------------------------------------------
// Per-head V transpose: Vp [B,S,D] bf16 -> Vt [B*H][DEPTH][S] bf16
// ---------------------------------------------------------------------------
__global__ __launch_bounds__(256) void transpose_v(const unsigned short* __restrict__ Vp,
                                                   unsigned short* __restrict__ Vt) {
  __shared__ unsigned short tile[64][72];  // tile[d][s_local]
  int tid = threadIdx.x;
  int sb = blockIdx.x;   // 0..31
  int bh = blockIdx.y;   // 0..63
  int b = bh >> 4, h = bh & 15;
  int s0 = sb * 64;
#pragma unroll
  for (int rep = 0; rep < 2; ++rep) {
    int idx = rep * 256 + tid;
    int r = idx >> 3, c8 = idx & 7;
    us8 v = *(const us8*)(Vp + (size_t)(b * S_LEN + s0 + r) * D_MODEL + h * DEPTH + c8 * 8);
#pragma unroll
    for (int e = 0; e < 8; ++e) tile[c8 * 8 + e][r] = v[e];
  }
  __syncthreads();
#pragma unroll
  for (int rep = 0; rep < 2; ++rep) {
    int idx = rep * 256 + tid;
    int d = idx >> 3, c8 = idx & 7;
    us8 v = *(const us8*)&tile[d][c8 * 8];
    *(us8*)(Vt + ((size_t)(bh * DEPTH + d)) * S_LEN + s0 + c8 * 8) = v;
  }
}

// ---------------------------------------------------------------------------
// GEMM:  C[M][N] = A[M][K] @ Bt[N][K]^T + bias*bscale
// Best-measured form (r9: QKV ~97us, total 178.4): 128x128 tile, 4 waves,
// reg-staged 2-barrier K-loop + T14 register prefetch of tile k+1 for BOTH
// operands, issued right after the visibility barrier so global latency
// hides under the 32 MFMAs. bf16-A path (AO): A via global_load_lds with
// XOR-swizzled source + matching read XOR, B reg-prefetched.
// No min-waves bound anywhere (r6/r8: silent spill catastrophes).
// Rejected by measurement: BM=256@512thr (r12: VGPR 80 -> serialized
// prefetch), 8-phase BN=128 (r11: half MFMA/barrier + cast3 tax), B-pad 76
// (r10: conflicts halved, no speedup — conflicts not on critical path).
// ---------------------------------------------------------------------------
struct GemmSlice {
  const void* A;
  const unsigned short* Bt;
  const float* bias;
  void* C;
  float bscale;
};
struct GemmArgs {
  GemmSlice s[3];
};

template <bool A_IS_F32, bool OUT_F32>
__global__ __launch_bounds__(256) void gemm_bt(GemmArgs args, int M, int N, int K) {
  constexpr int ASTR = A_IS_F32 ? 72 : 64;
  __shared__ unsigned short a_lds[128 * ASTR];
  __shared__ unsigned short b_lds[128 * 72];

  int slice = blockIdx.y >> 3;
  int nj = blockIdx.y & 7;
  const GemmSlice& g = args.s[slice];
  const float* Af = (const float*)g.A;
  const unsigned short* Ah = (const unsigned short*)g.A;
  const unsigned short* Bt = g.Bt;

  int tid = threadIdx.x;
  int wave = tid >> 6, lane = tid & 63;
  int l15 = lane & 15, lg = lane >> 4;
  int wm = wave >> 1, wn = wave & 1;

  int row0 = blockIdx.x * 128;
  int col0 = nj * 128;

  f32x4 acc[4][4] = {};
  f32x4 av[8];  // in-flight A tile (fp32 path)
  us8 bv[4];    // in-flight B tile

  int ar = tid >> 4, ac4 = tid & 15;  // fp32-A staging coords
  int br = tid >> 3, bc8 = tid & 7;   // B staging coords

  auto loadA = [&](int k0) {
#pragma unroll
    for (int rep = 0; rep < 8; ++rep)
      av[rep] = *(const f32x4*)(Af + (size_t)(row0 + rep * 16 + ar) * K + k0 + ac4 * 4);
  };
  auto writeA = [&]() {
#pragma unroll
    for (int rep = 0; rep < 8; ++rep) {
      us4 h = {f2bf_hw(av[rep][0]), f2bf_hw(av[rep][1]),
               f2bf_hw(av[rep][2]), f2bf_hw(av[rep][3])};
      *(us4*)&a_lds[(rep * 16 + ar) * 72 + ac4 * 4] = h;
    }
  };
  auto loadB = [&](int k0) {
#pragma unroll
    for (int rep = 0; rep < 4; ++rep)
      bv[rep] = *(const us8*)(Bt + (size_t)(col0 + rep * 32 + br) * K + k0 + bc8 * 8);
  };
  auto writeB = [&]() {
#pragma unroll
    for (int rep = 0; rep < 4; ++rep)
      *(us8*)&b_lds[(rep * 32 + br) * 72 + bc8 * 8] = bv[rep];
  };
  auto issueA = [&](int k0) {  // bf16-A via glds, swizzled source
#pragma unroll
    for (int rep = 0; rep < 4; ++rep) {
      int chunk = (wave * 4 + rep) * 64 + lane;
      int row = chunk >> 3;
      int c8 = (chunk & 7) ^ (row & 7);
      __builtin_amdgcn_global_load_lds(
          (const GLOBAL_AS void*)(Ah + (size_t)(row0 + row) * K + k0 + c8 * 8),
          (LDS_AS void*)(&a_lds[chunk * 8]), 16, 0, 0);
    }
  };
  auto compute = [&]() {
#pragma unroll
    for (int kk = 0; kk < 2; ++kk) {
      bf16x8 af[4], bfr[4];
#pragma unroll
      for (int ii = 0; ii < 4; ++ii) {
        int row = wm * 64 + ii * 16 + l15;
        if constexpr (A_IS_F32)
          af[ii] = *(const bf16x8*)&a_lds[row * 72 + kk * 32 + lg * 8];
        else
          af[ii] = *(const bf16x8*)&a_lds[row * 64 + (((kk * 4 + lg) ^ (l15 & 7)) * 8)];
      }
#pragma unroll
      for (int jj = 0; jj < 4; ++jj) {
        int row = wn * 64 + jj * 16 + l15;
        bfr[jj] = *(const bf16x8*)&b_lds[row * 72 + kk * 32 + lg * 8];
      }
#pragma unroll
      for (int ii = 0; ii < 4; ++ii)
#pragma unroll
        for (int jj = 0; jj < 4; ++jj)
          acc[ii][jj] = __builtin_amdgcn_mfma_f32_16x16x32_bf16(af[ii], bfr[jj], acc[ii][jj], 0, 0, 0);
    }
  };

  int nk = K >> 6;
  loadB(0);
  if constexpr (A_IS_F32) loadA(0);

  for (int ki = 0; ki < nk; ++ki) {
    __syncthreads();  // readers of previous tile done
    writeB();
    if constexpr (A_IS_F32)
      writeA();
    else
      issueA(ki * 64);
    __syncthreads();  // tile visible (drains lgkm + vmcnt)
    if (ki + 1 < nk) {
      loadB((ki + 1) * 64);                    // T14: prefetch next tile's regs —
      if constexpr (A_IS_F32) loadA((ki + 1) * 64);  // latency hides under MFMAs
    }
    compute();
  }

  // ---- epilogue ----
#pragma unroll
  for (int ii = 0; ii < 4; ++ii) {
#pragma unroll
    for (int jj = 0; jj < 4; ++jj) {
      int col = col0 + wn * 64 + jj * 16 + l15;
      float bv2 = g.bias[col] * g.bscale;
#pragma unroll
      for (int r = 0; r < 4; ++r) {
        int row = row0 + wm * 64 + ii * 16 + lg * 4 + r;
        float v = acc[ii][jj][r] + bv2;
        if constexpr (OUT_F32)
          ((float*)g.C)[(size_t)row * N + col] = v;
        else
          ((unsigned short*)g.C)[(size_t)row * N + col] = f2bf(v);
      }
    }
  }
}

// ---------------------------------------------------------------------------
// Causal flash attention (best-measured form — 71.6us thrice under rocprof).
// Q pre-scaled by 0.125*log2(e); NO-MAX exp2 softmax (logits hard-bounded,
// O = P@V / P@1 is shift-invariant; masked lanes: exp2(-1e10) == +0);
// l via ones-MFMA on the SAME truncated-bf16 P (bias cancels in O/l).
// 8 waves x 16 q-rows, QBLK=128, pairs (p,15-p) -> uniform 36 steps.
// Single-buffered K/V^T (39 KB), two barriers/step, T14 reg prefetch.
// Plain bounds (r8: min-waves bound + co-compile regalloc -> spill).
// Rejected by measurement: 32 rows/wave at grid 512 (r10) and grid 1024
// (r13) — both lost to this config; dbuf K/V (r5) — neutral.
// ---------------------------------------------------------------------------
__global__ __launch_bounds__(512) void attn_kernel(const unsigned short* __restrict__ Qp,
                                                   const unsigned short* __restrict__ Kp,
                                                   const unsigned short* __restrict__ Vt,
                                                   unsigned short* __restrict__ Op) {
  __shared__ unsigned short k_lds[64][76];
  __shared__ unsigned short vt_lds[64][76];   // [d][k]
  __shared__ unsigned short p_lds[8][16][76];

  int tid = threadIdx.x;
  int w = tid >> 6, lane = tid & 63;
  int l15 = lane & 15, lg = lane >> 4;

  int bid = blockIdx.x;                    // 0..511
  int swz = (bid & 7) * 64 + (bid >> 3);   // bijective (512 % 8 == 0)
  int pairIdx = swz & 7;                   // 0..7
  int bh = swz >> 3;                       // 0..63 (8 bh per XCD)
  int b = bh >> 4, h = bh & 15;

  const unsigned short* Kbase = Kp + (size_t)b * S_LEN * D_MODEL + h * DEPTH;
  const unsigned short* Vbase = Vt + (size_t)bh * DEPTH * S_LEN;

  bool stageV = (tid >= 256);
  int st = tid & 255;
  int r = st >> 2, cb = (st & 3) * 16;
  const unsigned short* srow = stageV ? (Vbase + (size_t)r * S_LEN + cb)
                                      : (Kbase + (size_t)r * D_MODEL + cb);
  const size_t sstep = stageV ? 64 : (size_t)64 * D_MODEL;

  bf16x8 ones;
#pragma unroll
  for (int e = 0; e < 8; ++e) ones[e] = (short)0x3F80;

  for (int half = 0; half < 2; ++half) {
    int t = (half == 0) ? pairIdx : (15 - pairIdx);
    int q0 = t * 128;
    int nkv = 2 * t + 2;
    int q0w = q0 + w * 16;

    const unsigned short* qp =
        Qp + ((size_t)(b * S_LEN + q0 + w * 16 + l15)) * D_MODEL + h * DEPTH;
    bf16x8 qf0 = *(const bf16x8*)(qp + lg * 8);
    bf16x8 qf1 = *(const bf16x8*)(qp + 32 + lg * 8);

    f32x4 acc_l = (f32x4){0.f, 0.f, 0.f, 0.f};
    f32x4 acc_o[4];
#pragma unroll
    for (int dd = 0; dd < 4; ++dd) acc_o[dd] = (f32x4){0.f, 0.f, 0.f, 0.f};

    const unsigned short* sptr = srow;
    us8 s0 = *(const us8*)sptr;
    us8 s1 = *(const us8*)(sptr + 8);
    sptr += sstep;

    for (int kb = 0; kb < nkv; ++kb) {
      int k0 = kb * 64;
      __syncthreads();  // readers of tile kb-1 (or prior half) done
      if (stageV) {
        *(us8*)&vt_lds[r][cb] = s0;
        *(us8*)&vt_lds[r][cb + 8] = s1;
      } else {
        *(us8*)&k_lds[r][cb] = s0;
        *(us8*)&k_lds[r][cb + 8] = s1;
      }
      __syncthreads();  // tile kb visible
      bool more = (kb + 1) < nkv;
      if (more) {
        s0 = *(const us8*)sptr;        // T14: issue next tile's loads early
        s1 = *(const us8*)(sptr + 8);
        sptr += sstep;
      }

      bool full_masked = (k0 > q0w + 15);
      if (!full_masked) {
        f32x4 s[4];
#pragma unroll
        for (int nf = 0; nf < 4; ++nf) s[nf] = (f32x4){0.f, 0.f, 0.f, 0.f};
        __builtin_amdgcn_s_setprio(1);
#pragma unroll
        for (int nf = 0; nf < 4; ++nf) {
          bf16x8 kf0 = *(const bf16x8*)&k_lds[nf * 16 + l15][lg * 8];
          bf16x8 kf1 = *(const bf16x8*)&k_lds[nf * 16 + l15][32 + lg * 8];
          s[nf] = __builtin_amdgcn_mfma_f32_16x16x32_bf16(qf0, kf0, s[nf], 0, 0, 0);
          s[nf] = __builtin_amdgcn_mfma_f32_16x16x32_bf16(qf1, kf1, s[nf], 0, 0, 0);
        }
        __builtin_amdgcn_s_setprio(0);

        bool diag = (k0 + 63 > q0w);
        if (diag) {
#pragma unroll
          for (int nf = 0; nf < 4; ++nf)
#pragma unroll
            for (int rr = 0; rr < 4; ++rr) {
              int qrow = q0w + lg * 4 + rr;
              int kcol = k0 + nf * 16 + l15;
              float x = (kcol > qrow) ? -1e10f : s[nf][rr];
              float p = __builtin_amdgcn_exp2f(x);
              p_lds[w][lg * 4 + rr][nf * 16 + l15] =
                  (unsigned short)(__builtin_bit_cast(unsigned int, p) >> 16);
            }
        } else {
#pragma unroll
          for (int nf = 0; nf < 4; ++nf)
#pragma unroll
            for (int rr = 0; rr < 4; ++rr) {
              float p = __builtin_amdgcn_exp2f(s[nf][rr]);
              p_lds[w][lg * 4 + rr][nf * 16 + l15] =
                  (unsigned short)(__builtin_bit_cast(unsigned int, p) >> 16);
            }
        }

        __builtin_amdgcn_s_setprio(1);
#pragma unroll
        for (int kk = 0; kk < 2; ++kk) {
          bf16x8 pf = *(const bf16x8*)&p_lds[w][l15][kk * 32 + lg * 8];
          acc_l = __builtin_amdgcn_mfma_f32_16x16x32_bf16(pf, ones, acc_l, 0, 0, 0);
#pragma unroll
          for (int dd = 0; dd < 4; ++dd) {
            bf16x8 vf = *(const bf16x8*)&vt_lds[dd * 16 + l15][kk * 32 + lg * 8];
            acc_o[dd] = __builtin_amdgcn_mfma_f32_16x16x32_bf16(pf, vf, acc_o[dd], 0, 0, 0);
          }
        }
        __builtin_amdgcn_s_setprio(0);
      }
    }

#pragma unroll
    for (int rr = 0; rr < 4; ++rr) {
      float inv = 1.0f / acc_l[rr];
      int qrow = q0 + w * 16 + lg * 4 + rr;
      unsigned short* op = Op + ((size_t)(b * S_LEN + qrow)) * D_MODEL + h * DEPTH;
#pragma unroll
      for (int dd = 0; dd < 4; ++dd)
        op[dd * 16 + l15] = f2bf(acc_o[dd][rr] * inv);
    }
  }
}

// ---------------------------------------------------------------------------
extern "C" void kernel_launch(void* const* d_in, const int* in_sizes, int n_in,
                              void* d_out, int out_size, void* d_ws, size_t ws_size,
                              hipStream_t stream) {
  const float* q  = (const float*)d_in[0];
  const float* v  = (const float*)d_in[1];
  const float* k  = (const float*)d_in[2];
  const float* Wq = (const float*)d_in[3];
  const float* bq = (const float*)d_in[4];
  const float* Wk = (const float*)d_in[5];
  const float* bk = (const float*)d_in[6];
  const float* Wv = (const float*)d_in[7];
  const float* bv = (const float*)d_in[8];
  const float* Wo = (const float*)d_in[9];
  const float* bo = (const float*)d_in[10];

  char* ws = (char*)d_ws;
  const size_t WSZ = (size_t)D_MODEL * D_MODEL * 2;        // 2 MB per weight
  const size_t XSZ = (size_t)BATCH * S_LEN * D_MODEL * 2;  // 16 MB per activation
  unsigned short* Wqt = (unsigned short*)(ws);
  unsigned short* Wkt = (unsigned short*)(ws + WSZ);
  unsigned short* Wvt = (unsigned short*)(ws + 2 * WSZ);
  unsigned short* Wot = (unsigned short*)(ws + 3 * WSZ);
  unsigned short* Qp  = (unsigned short*)(ws + 4 * WSZ);
  unsigned short* Kp  = (unsigned short*)(ws + 4 * WSZ + XSZ);
  unsigned short* Vp  = (unsigned short*)(ws + 4 * WSZ + 2 * XSZ);
  unsigned short* Vtp = (unsigned short*)(ws + 4 * WSZ + 3 * XSZ);
  unsigned short* AO  = Vp;  // alias: Vp fully consumed by transpose_v before attn writes AO

  const float SCL = 0.125f * 1.4426950408889634f;
  const int M = BATCH * S_LEN;

  TCArgs tc{};
  tc.W[0] = Wq;  tc.Wt[0] = Wqt;  tc.scale[0] = SCL;
  tc.W[1] = Wk;  tc.Wt[1] = Wkt;  tc.scale[1] = 1.0f;
  tc.W[2] = Wv;  tc.Wt[2] = Wvt;  tc.scale[2] = 1.0f;
  tc.W[3] = Wo;  tc.Wt[3] = Wot;  tc.scale[3] = 1.0f;
  hipLaunchKernelGGL(transpose_cast4, dim3(D_MODEL / 32, D_MODEL / 32, 4), dim3(32, 8),
                     0, stream, tc, D_MODEL);

  GemmArgs qkv{};
  qkv.s[0] = GemmSlice{(const void*)q, Wqt, bq, (void*)Qp, SCL};
  qkv.s[1] = GemmSlice{(const void*)k, Wkt, bk, (void*)Kp, 1.0f};
  qkv.s[2] = GemmSlice{(const void*)v, Wvt, bv, (void*)Vp, 1.0f};
  hipLaunchKernelGGL((gemm_bt<true, false>), dim3(M / 128, 24), dim3(256), 0, stream,
                     qkv, M, D_MODEL, D_MODEL);

  hipLaunchKernelGGL(transpose_v, dim3(S_LEN / 64, BATCH * N_HEADS), dim3(256), 0, stream,
                     Vp, Vtp);

  hipLaunchKernelGGL(attn_kernel, dim3(512), dim3(512), 0, stream, Qp, Kp, Vtp, AO);

  GemmArgs ao{};
  ao.s[0] = GemmSlice{(const void*)AO, Wot, bo, d_out, 1.0f};
  hipLaunchKernelGGL((gemm_bt<false, true>), dim3(M / 128, 8), dim3(256), 0, stream,
                     ao, M, D_MODEL, D_MODEL);
}

// Round 16
// 178.184 us; speedup vs baseline: 1.1155x; 1.0017x over previous
//
#include <hip/hip_runtime.h>
#include <hip/hip_bf16.h>
#include <cstdint>
#include <cstddef>

#define S_LEN 2048
#define D_MODEL 1024
#define N_HEADS 16
#define DEPTH 64
#define BATCH 4

#define GLOBAL_AS __attribute__((address_space(1)))
#define LDS_AS __attribute__((address_space(3)))

typedef __attribute__((ext_vector_type(4))) float f32x4;
typedef __attribute__((ext_vector_type(8))) short bf16x8;
typedef __attribute__((ext_vector_type(4))) unsigned short us4;
typedef __attribute__((ext_vector_type(8))) unsigned short us8;

__device__ __forceinline__ unsigned short f2bf(float f) {
  unsigned int u = __builtin_bit_cast(unsigned int, f);
  u += 0x7FFFu + ((u >> 16) & 1u);   // round-to-nearest-even
  return (unsigned short)(u >> 16);
}

// HW cast (compiler emits v_cvt_pk_bf16_f32 pairs)
__device__ __forceinline__ unsigned short f2bf_hw(float f) {
  return __builtin_bit_cast(unsigned short, __float2bfloat16(f));
}

// ---------------------------------------------------------------------------
// Fused weight transpose + scale + fp32 -> bf16 cast for all 4 weights:
// Wt[n][k] = W[k][n] * scale.  grid.z selects the weight.
// ---------------------------------------------------------------------------
struct TCArgs {
  const float* W[4];
  unsigned short* Wt[4];
  float scale[4];
};

__global__ __launch_bounds__(256) void transpose_cast4(TCArgs a, int N) {
  __shared__ float tile[32][33];
  int z = blockIdx.z;
  const float* W = a.W[z];
  unsigned short* Wt = a.Wt[z];
  float scale = a.scale[z];
  int bx = blockIdx.x * 32;  // n-range
  int by = blockIdx.y * 32;  // k-range
  int tx = threadIdx.x, ty = threadIdx.y;  // 32 x 8
#pragma unroll
  for (int i = 0; i < 4; ++i)
    tile[ty + i * 8][tx] = W[(size_t)(by + ty + i * 8) * N + bx + tx];
  __syncthreads();
#pragma unroll
  for (int i = 0; i < 4; ++i)
    Wt[(size_t)(bx + ty + i * 8) * N + by + tx] = f2bf(tile[tx][ty + i * 8] * scale);
}

// ---------------------------------------------------------------------------
// GEMM:  C[M][N] = A[M][K] @ Bt[N][K]^T + bias*bscale
// Best-measured form (r9/r15: total 178.4): 128x128 tile, 4 waves,
// reg-staged 2-barrier K-loop + T14 register prefetch of tile k+1 for BOTH
// operands. bf16-A path (AO): A via global_load_lds with XOR-swizzled
// source + matching read XOR, B reg-prefetched. No min-waves bound.
// NEW (r15): per-slice vtrans flag — the V slice's epilogue writes directly
// in per-head-transposed layout Vt[bh][d][s] (us4 stores, 4 consecutive s),
// eliminating the separate transpose_v kernel (~6us + 32MB traffic).
// Rejected by measurement: BM=256@512thr (r12), 8-phase BN=128 (r11),
// B-pad 76 (r10), min-waves bounds (r6/r8).
// ---------------------------------------------------------------------------
struct GemmSlice {
  const void* A;
  const unsigned short* Bt;
  const float* bias;
  void* C;
  float bscale;
  int vtrans;   // 1 = write bf16 output transposed per-head into Vt[bh][d][s]
};
struct GemmArgs {
  GemmSlice s[3];
};

template <bool A_IS_F32, bool OUT_F32>
__global__ __launch_bounds__(256) void gemm_bt(GemmArgs args, int M, int N, int K) {
  constexpr int ASTR = A_IS_F32 ? 72 : 64;
  __shared__ unsigned short a_lds[128 * ASTR];
  __shared__ unsigned short b_lds[128 * 72];

  int slice = blockIdx.y >> 3;
  int nj = blockIdx.y & 7;
  const GemmSlice& g = args.s[slice];
  const float* Af = (const float*)g.A;
  const unsigned short* Ah = (const unsigned short*)g.A;
  const unsigned short* Bt = g.Bt;

  int tid = threadIdx.x;
  int wave = tid >> 6, lane = tid & 63;
  int l15 = lane & 15, lg = lane >> 4;
  int wm = wave >> 1, wn = wave & 1;

  int row0 = blockIdx.x * 128;
  int col0 = nj * 128;

  f32x4 acc[4][4] = {};
  f32x4 av[8];  // in-flight A tile (fp32 path)
  us8 bv[4];    // in-flight B tile

  int ar = tid >> 4, ac4 = tid & 15;  // fp32-A staging coords
  int br = tid >> 3, bc8 = tid & 7;   // B staging coords

  auto loadA = [&](int k0) {
#pragma unroll
    for (int rep = 0; rep < 8; ++rep)
      av[rep] = *(const f32x4*)(Af + (size_t)(row0 + rep * 16 + ar) * K + k0 + ac4 * 4);
  };
  auto writeA = [&]() {
#pragma unroll
    for (int rep = 0; rep < 8; ++rep) {
      us4 h = {f2bf_hw(av[rep][0]), f2bf_hw(av[rep][1]),
               f2bf_hw(av[rep][2]), f2bf_hw(av[rep][3])};
      *(us4*)&a_lds[(rep * 16 + ar) * 72 + ac4 * 4] = h;
    }
  };
  auto loadB = [&](int k0) {
#pragma unroll
    for (int rep = 0; rep < 4; ++rep)
      bv[rep] = *(const us8*)(Bt + (size_t)(col0 + rep * 32 + br) * K + k0 + bc8 * 8);
  };
  auto writeB = [&]() {
#pragma unroll
    for (int rep = 0; rep < 4; ++rep)
      *(us8*)&b_lds[(rep * 32 + br) * 72 + bc8 * 8] = bv[rep];
  };
  auto issueA = [&](int k0) {  // bf16-A via glds, swizzled source
#pragma unroll
    for (int rep = 0; rep < 4; ++rep) {
      int chunk = (wave * 4 + rep) * 64 + lane;
      int row = chunk >> 3;
      int c8 = (chunk & 7) ^ (row & 7);
      __builtin_amdgcn_global_load_lds(
          (const GLOBAL_AS void*)(Ah + (size_t)(row0 + row) * K + k0 + c8 * 8),
          (LDS_AS void*)(&a_lds[chunk * 8]), 16, 0, 0);
    }
  };
  auto compute = [&]() {
#pragma unroll
    for (int kk = 0; kk < 2; ++kk) {
      bf16x8 af[4], bfr[4];
#pragma unroll
      for (int ii = 0; ii < 4; ++ii) {
        int row = wm * 64 + ii * 16 + l15;
        if constexpr (A_IS_F32)
          af[ii] = *(const bf16x8*)&a_lds[row * 72 + kk * 32 + lg * 8];
        else
          af[ii] = *(const bf16x8*)&a_lds[row * 64 + (((kk * 4 + lg) ^ (l15 & 7)) * 8)];
      }
#pragma unroll
      for (int jj = 0; jj < 4; ++jj) {
        int row = wn * 64 + jj * 16 + l15;
        bfr[jj] = *(const bf16x8*)&b_lds[row * 72 + kk * 32 + lg * 8];
      }
#pragma unroll
      for (int ii = 0; ii < 4; ++ii)
#pragma unroll
        for (int jj = 0; jj < 4; ++jj)
          acc[ii][jj] = __builtin_amdgcn_mfma_f32_16x16x32_bf16(af[ii], bfr[jj], acc[ii][jj], 0, 0, 0);
    }
  };

  int nk = K >> 6;
  loadB(0);
  if constexpr (A_IS_F32) loadA(0);

  for (int ki = 0; ki < nk; ++ki) {
    __syncthreads();  // readers of previous tile done
    writeB();
    if constexpr (A_IS_F32)
      writeA();
    else
      issueA(ki * 64);
    __syncthreads();  // tile visible (drains lgkm + vmcnt)
    if (ki + 1 < nk) {
      loadB((ki + 1) * 64);                    // T14: prefetch next tile's regs —
      if constexpr (A_IS_F32) loadA((ki + 1) * 64);  // latency hides under MFMAs
    }
    compute();
  }

  // ---- epilogue ----
#pragma unroll
  for (int ii = 0; ii < 4; ++ii) {
#pragma unroll
    for (int jj = 0; jj < 4; ++jj) {
      int col = col0 + wn * 64 + jj * 16 + l15;
      float bv2 = g.bias[col] * g.bscale;
      int rowb = row0 + wm * 64 + ii * 16 + lg * 4;
      if constexpr (OUT_F32) {
#pragma unroll
        for (int r = 0; r < 4; ++r)
          ((float*)g.C)[(size_t)(rowb + r) * N + col] = acc[ii][jj][r] + bv2;
      } else {
        if (g.vtrans) {
          // V slice: write directly as Vt[bh][d][s]; 4 consecutive s -> us4.
          int b = rowb >> 11, s = rowb & 2047;     // S_LEN == 2048
          int h = col >> 6, d = col & 63;          // DEPTH == 64
          us4 o = {f2bf(acc[ii][jj][0] + bv2), f2bf(acc[ii][jj][1] + bv2),
                   f2bf(acc[ii][jj][2] + bv2), f2bf(acc[ii][jj][3] + bv2)};
          *(us4*)((unsigned short*)g.C +
                  ((size_t)((b * N_HEADS + h) * DEPTH + d)) * S_LEN + s) = o;
        } else {
#pragma unroll
          for (int r = 0; r < 4; ++r)
            ((unsigned short*)g.C)[(size_t)(rowb + r) * N + col] =
                f2bf(acc[ii][jj][r] + bv2);
        }
      }
    }
  }
}

// ---------------------------------------------------------------------------
// Causal flash attention (best-measured form — locked since r9).
// Q pre-scaled by 0.125*log2(e); NO-MAX exp2 softmax (logits hard-bounded,
// O = P@V / P@1 is shift-invariant; masked lanes: exp2(-1e10) == +0);
// l via ones-MFMA on the SAME truncated-bf16 P (bias cancels in O/l).
// 8 waves x 16 q-rows, QBLK=128, pairs (p,15-p) -> uniform 36 steps.
// Single-buffered K/V^T (39 KB), two barriers/step, T14 reg prefetch.
// Plain bounds (r8: min-waves bound + co-compile regalloc -> spill).
// ---------------------------------------------------------------------------
__global__ __launch_bounds__(512) void attn_kernel(const unsigned short* __restrict__ Qp,
                                                   const unsigned short* __restrict__ Kp,
                                                   const unsigned short* __restrict__ Vt,
                                                   unsigned short* __restrict__ Op) {
  __shared__ unsigned short k_lds[64][76];
  __shared__ unsigned short vt_lds[64][76];   // [d][k]
  __shared__ unsigned short p_lds[8][16][76];

  int tid = threadIdx.x;
  int w = tid >> 6, lane = tid & 63;
  int l15 = lane & 15, lg = lane >> 4;

  int bid = blockIdx.x;                    // 0..511
  int swz = (bid & 7) * 64 + (bid >> 3);   // bijective (512 % 8 == 0)
  int pairIdx = swz & 7;                   // 0..7
  int bh = swz >> 3;                       // 0..63 (8 bh per XCD)
  int b = bh >> 4, h = bh & 15;

  const unsigned short* Kbase = Kp + (size_t)b * S_LEN * D_MODEL + h * DEPTH;
  const unsigned short* Vbase = Vt + (size_t)bh * DEPTH * S_LEN;

  bool stageV = (tid >= 256);
  int st = tid & 255;
  int r = st >> 2, cb = (st & 3) * 16;
  const unsigned short* srow = stageV ? (Vbase + (size_t)r * S_LEN + cb)
                                      : (Kbase + (size_t)r * D_MODEL + cb);
  const size_t sstep = stageV ? 64 : (size_t)64 * D_MODEL;

  bf16x8 ones;
#pragma unroll
  for (int e = 0; e < 8; ++e) ones[e] = (short)0x3F80;

  for (int half = 0; half < 2; ++half) {
    int t = (half == 0) ? pairIdx : (15 - pairIdx);
    int q0 = t * 128;
    int nkv = 2 * t + 2;
    int q0w = q0 + w * 16;

    const unsigned short* qp =
        Qp + ((size_t)(b * S_LEN + q0 + w * 16 + l15)) * D_MODEL + h * DEPTH;
    bf16x8 qf0 = *(const bf16x8*)(qp + lg * 8);
    bf16x8 qf1 = *(const bf16x8*)(qp + 32 + lg * 8);

    f32x4 acc_l = (f32x4){0.f, 0.f, 0.f, 0.f};
    f32x4 acc_o[4];
#pragma unroll
    for (int dd = 0; dd < 4; ++dd) acc_o[dd] = (f32x4){0.f, 0.f, 0.f, 0.f};

    const unsigned short* sptr = srow;
    us8 s0 = *(const us8*)sptr;
    us8 s1 = *(const us8*)(sptr + 8);
    sptr += sstep;

    for (int kb = 0; kb < nkv; ++kb) {
      int k0 = kb * 64;
      __syncthreads();  // readers of tile kb-1 (or prior half) done
      if (stageV) {
        *(us8*)&vt_lds[r][cb] = s0;
        *(us8*)&vt_lds[r][cb + 8] = s1;
      } else {
        *(us8*)&k_lds[r][cb] = s0;
        *(us8*)&k_lds[r][cb + 8] = s1;
      }
      __syncthreads();  // tile kb visible
      bool more = (kb + 1) < nkv;
      if (more) {
        s0 = *(const us8*)sptr;        // T14: issue next tile's loads early
        s1 = *(const us8*)(sptr + 8);
        sptr += sstep;
      }

      bool full_masked = (k0 > q0w + 15);
      if (!full_masked) {
        f32x4 s[4];
#pragma unroll
        for (int nf = 0; nf < 4; ++nf) s[nf] = (f32x4){0.f, 0.f, 0.f, 0.f};
        __builtin_amdgcn_s_setprio(1);
#pragma unroll
        for (int nf = 0; nf < 4; ++nf) {
          bf16x8 kf0 = *(const bf16x8*)&k_lds[nf * 16 + l15][lg * 8];
          bf16x8 kf1 = *(const bf16x8*)&k_lds[nf * 16 + l15][32 + lg * 8];
          s[nf] = __builtin_amdgcn_mfma_f32_16x16x32_bf16(qf0, kf0, s[nf], 0, 0, 0);
          s[nf] = __builtin_amdgcn_mfma_f32_16x16x32_bf16(qf1, kf1, s[nf], 0, 0, 0);
        }
        __builtin_amdgcn_s_setprio(0);

        bool diag = (k0 + 63 > q0w);
        if (diag) {
#pragma unroll
          for (int nf = 0; nf < 4; ++nf)
#pragma unroll
            for (int rr = 0; rr < 4; ++rr) {
              int qrow = q0w + lg * 4 + rr;
              int kcol = k0 + nf * 16 + l15;
              float x = (kcol > qrow) ? -1e10f : s[nf][rr];
              float p = __builtin_amdgcn_exp2f(x);
              p_lds[w][lg * 4 + rr][nf * 16 + l15] =
                  (unsigned short)(__builtin_bit_cast(unsigned int, p) >> 16);
            }
        } else {
#pragma unroll
          for (int nf = 0; nf < 4; ++nf)
#pragma unroll
            for (int rr = 0; rr < 4; ++rr) {
              float p = __builtin_amdgcn_exp2f(s[nf][rr]);
              p_lds[w][lg * 4 + rr][nf * 16 + l15] =
                  (unsigned short)(__builtin_bit_cast(unsigned int, p) >> 16);
            }
        }

        __builtin_amdgcn_s_setprio(1);
#pragma unroll
        for (int kk = 0; kk < 2; ++kk) {
          bf16x8 pf = *(const bf16x8*)&p_lds[w][l15][kk * 32 + lg * 8];
          acc_l = __builtin_amdgcn_mfma_f32_16x16x32_bf16(pf, ones, acc_l, 0, 0, 0);
#pragma unroll
          for (int dd = 0; dd < 4; ++dd) {
            bf16x8 vf = *(const bf16x8*)&vt_lds[dd * 16 + l15][kk * 32 + lg * 8];
            acc_o[dd] = __builtin_amdgcn_mfma_f32_16x16x32_bf16(pf, vf, acc_o[dd], 0, 0, 0);
          }
        }
        __builtin_amdgcn_s_setprio(0);
      }
    }

#pragma unroll
    for (int rr = 0; rr < 4; ++rr) {
      float inv = 1.0f / acc_l[rr];
      int qrow = q0 + w * 16 + lg * 4 + rr;
      unsigned short* op = Op + ((size_t)(b * S_LEN + qrow)) * D_MODEL + h * DEPTH;
#pragma unroll
      for (int dd = 0; dd < 4; ++dd)
        op[dd * 16 + l15] = f2bf(acc_o[dd][rr] * inv);
    }
  }
}

// ---------------------------------------------------------------------------
extern "C" void kernel_launch(void* const* d_in, const int* in_sizes, int n_in,
                              void* d_out, int out_size, void* d_ws, size_t ws_size,
                              hipStream_t stream) {
  const float* q  = (const float*)d_in[0];
  const float* v  = (const float*)d_in[1];
  const float* k  = (const float*)d_in[2];
  const float* Wq = (const float*)d_in[3];
  const float* bq = (const float*)d_in[4];
  const float* Wk = (const float*)d_in[5];
  const float* bk = (const float*)d_in[6];
  const float* Wv = (const float*)d_in[7];
  const float* bv = (const float*)d_in[8];
  const float* Wo = (const float*)d_in[9];
  const float* bo = (const float*)d_in[10];

  char* ws = (char*)d_ws;
  const size_t WSZ = (size_t)D_MODEL * D_MODEL * 2;        // 2 MB per weight
  const size_t XSZ = (size_t)BATCH * S_LEN * D_MODEL * 2;  // 16 MB per activation
  unsigned short* Wqt = (unsigned short*)(ws);
  unsigned short* Wkt = (unsigned short*)(ws + WSZ);
  unsigned short* Wvt = (unsigned short*)(ws + 2 * WSZ);
  unsigned short* Wot = (unsigned short*)(ws + 3 * WSZ);
  unsigned short* Qp  = (unsigned short*)(ws + 4 * WSZ);
  unsigned short* Kp  = (unsigned short*)(ws + 4 * WSZ + XSZ);
  unsigned short* AO  = (unsigned short*)(ws + 4 * WSZ + 2 * XSZ);
  unsigned short* Vtp = (unsigned short*)(ws + 4 * WSZ + 3 * XSZ);  // V-GEMM writes transposed

  const float SCL = 0.125f * 1.4426950408889634f;
  const int M = BATCH * S_LEN;

  TCArgs tc{};
  tc.W[0] = Wq;  tc.Wt[0] = Wqt;  tc.scale[0] = SCL;
  tc.W[1] = Wk;  tc.Wt[1] = Wkt;  tc.scale[1] = 1.0f;
  tc.W[2] = Wv;  tc.Wt[2] = Wvt;  tc.scale[2] = 1.0f;
  tc.W[3] = Wo;  tc.Wt[3] = Wot;  tc.scale[3] = 1.0f;
  hipLaunchKernelGGL(transpose_cast4, dim3(D_MODEL / 32, D_MODEL / 32, 4), dim3(32, 8),
                     0, stream, tc, D_MODEL);

  GemmArgs qkv{};
  qkv.s[0] = GemmSlice{(const void*)q, Wqt, bq, (void*)Qp, SCL, 0};
  qkv.s[1] = GemmSlice{(const void*)k, Wkt, bk, (void*)Kp, 1.0f, 0};
  qkv.s[2] = GemmSlice{(const void*)v, Wvt, bv, (void*)Vtp, 1.0f, 1};  // direct V^T
  hipLaunchKernelGGL((gemm_bt<true, false>), dim3(M / 128, 24), dim3(256), 0, stream,
                     qkv, M, D_MODEL, D_MODEL);

  hipLaunchKernelGGL(attn_kernel, dim3(512), dim3(512), 0, stream, Qp, Kp, Vtp, AO);

  GemmArgs ao{};
  ao.s[0] = GemmSlice{(const void*)AO, Wot, bo, d_out, 1.0f, 0};
  hipLaunchKernelGGL((gemm_bt<false, true>), dim3(M / 128, 8), dim3(256), 0, stream,
                     ao, M, D_MODEL, D_MODEL);
}